// Round 3
// 449.004 us; speedup vs baseline: 1.1735x; 1.1735x over previous
//
#include <hip/hip_runtime.h>
#include <hip/hip_bf16.h>

#define KK 50      // triples per (b,t)
#define DD 100
#define TWO_D 200
#define DPAD 112   // padded output-feature dim (7 * 16)
#define KHT 224    // padded K for head_tail gemm (7 * 32)
#define KRL 128    // padded K for relation gemm (4 * 32)

#define XHT_PITCH 232   // bf16 elems/row: 224 + 8 stagger pad; 464 B
#define XRL_PITCH 136   // 128 + 8; 272 B

#define NCHUNK (KK * 3 * 25)   // 3750 gather chunks per block

// workspace layout (bytes)
#define WS_FLAGS 0
#define WS_WHT 256                       // bf16[DPAD*KHT]  = 50176 B
#define WS_WRL (WS_WHT + DPAD*KHT*2)     // bf16[DPAD*KRL]  = 28672 B
#define WS_BHT (WS_WRL + DPAD*KRL*2)     // bf16[DPAD] (256 B slot)
#define WS_BRL (WS_BHT + 256)

typedef __attribute__((ext_vector_type(8))) short   s8v;
typedef __attribute__((ext_vector_type(8))) __bf16  b8v;
typedef __attribute__((ext_vector_type(4))) __bf16  b4v;
typedef __attribute__((ext_vector_type(4))) float   f32x4;

// --- MFMA shim: tolerate either builtin signature (short8 or bf16x8 operands) ---
template <typename T>
__device__ __forceinline__ auto mfma_try(T a, T b, f32x4 c, int)
    -> decltype(__builtin_amdgcn_mfma_f32_16x16x32_bf16(a, b, c, 0, 0, 0)) {
    return __builtin_amdgcn_mfma_f32_16x16x32_bf16(a, b, c, 0, 0, 0);
}
template <typename T, typename U = b8v>
__device__ __forceinline__ f32x4 mfma_try(T a, T b, f32x4 c, long) {
    U ab = __builtin_bit_cast(U, a);
    U bb = __builtin_bit_cast(U, b);
    return __builtin_amdgcn_mfma_f32_16x16x32_bf16(ab, bb, c, 0, 0, 0);
}
__device__ __forceinline__ f32x4 mfma16x16x32_bf16(s8v a, s8v b, f32x4 c) {
    return mfma_try(a, b, c, 0);
}

__device__ __forceinline__ float bf2f(__hip_bfloat16 h) { return __bfloat162float(h); }

__device__ __forceinline__ float tanh_fast(float x) {
    // tanh(x) = 1 - 2/(exp(2x)+1); exp->inf -> rcp=0 -> 1; exp->0 -> -1; tanh(0)=0 exact.
    float e = __expf(2.f * x);
    return 1.f - 2.f * __builtin_amdgcn_rcpf(e + 1.f);
}

// ---------- dtype detection (wave-parallel: ~5 loads/lane, ballot reduce) ----------
// fp32 read as two bf16 halves shows impossible exponents (emb ~ N(0,0.02^2)).
// int64 ids (< 2^32): all odd int32 slots are zero; int32 ids: ~none are.
__global__ void detect_dtypes(const unsigned int* __restrict__ emb_raw,
                              const unsigned int* __restrict__ ids_raw,
                              int* __restrict__ flags) {
    const int lane = threadIdx.x;   // 64 threads, 1 block
    int f32 = 0;
    #pragma unroll
    for (int rep = 0; rep < 4; rep++) {
        unsigned int w = emb_raw[lane + rep * 64];
        unsigned int e0 = (w >> 7)  & 0xFF;
        unsigned int e1 = (w >> 23) & 0xFF;
        if (e0 >= 0x87 || e1 >= 0x87) f32 = 1;   // |x| >= 256 impossible for real data
    }
    unsigned long long mf = __ballot(f32 != 0);
    unsigned long long mz = __ballot(ids_raw[2 * lane + 1] == 0u);
    if (lane == 0) {
        flags[0] = mf ? 1 : 0;
        flags[1] = (__popcll(mz) >= 32) ? 1 : 0;
    }
}

// ---------- canonicalize weights into zero-padded bf16 tiles in workspace ----------
__global__ void prep_weights(const void* __restrict__ Wht, const void* __restrict__ bht,
                             const void* __restrict__ Wrl, const void* __restrict__ brl,
                             void* __restrict__ ws) {
    const int* flags = (const int*)ws;
    const bool f32 = flags[0] != 0;
    __hip_bfloat16* whtp = (__hip_bfloat16*)((char*)ws + WS_WHT);
    __hip_bfloat16* wrlp = (__hip_bfloat16*)((char*)ws + WS_WRL);
    __hip_bfloat16* bhtp = (__hip_bfloat16*)((char*)ws + WS_BHT);
    __hip_bfloat16* brlp = (__hip_bfloat16*)((char*)ws + WS_BRL);

    const int gid = blockIdx.x * blockDim.x + threadIdx.x;
    const int gs  = gridDim.x * blockDim.x;

    for (int i = gid; i < DPAD * KHT; i += gs) {
        int d = i / KHT, f = i - d * KHT;
        float v = 0.f;
        if (d < DD && f < TWO_D)
            v = f32 ? ((const float*)Wht)[d * TWO_D + f]
                    : bf2f(((const __hip_bfloat16*)Wht)[d * TWO_D + f]);
        whtp[i] = __float2bfloat16(v);
    }
    for (int i = gid; i < DPAD * KRL; i += gs) {
        int d = i / KRL, f = i - d * KRL;
        float v = 0.f;
        if (d < DD && f < DD)
            v = f32 ? ((const float*)Wrl)[d * DD + f]
                    : bf2f(((const __hip_bfloat16*)Wrl)[d * DD + f]);
        wrlp[i] = __float2bfloat16(v);
    }
    for (int i = gid; i < DPAD; i += gs) {
        float vh = 0.f, vr = 0.f;
        if (i < DD) {
            vh = f32 ? ((const float*)bht)[i] : bf2f(((const __hip_bfloat16*)bht)[i]);
            vr = f32 ? ((const float*)brl)[i] : bf2f(((const __hip_bfloat16*)brl)[i]);
        }
        bhtp[i] = __float2bfloat16(vh);
        brlp[i] = __float2bfloat16(vr);
    }
}

// ---------- gather destination: LDS byte-offset relative to sXht base ----------
// sXrl is placed immediately after sXht in a single shared array so one int
// offset addresses both; -1 = skip (tail lanes).
#define XHT_BYTES (KK * XHT_PITCH * 2)
#define XRL_BYTES (KK * XRL_PITCH * 2)

__device__ __forceinline__ int gather_dst_off(int c) {
    // c in [0, NCHUNK): seg = c/25, off = (c%25)*4 elems
    int seg = c / 25;
    int off = (c - seg * 25) * 4;
    int r = seg / 3, wh = seg - r * 3;   // 0=head 1=relation 2=tail
    if (wh == 1) return XHT_BYTES + (r * XRL_PITCH + off) * 2;
    return (r * XHT_PITCH + (wh ? DD : 0) + off) * 2;
}

// ---------- batched gather: issue CNT independent loads, THEN write LDS ----------
template <int CNT>
__device__ __forceinline__ void gather_f32(const float* __restrict__ embf,
                                           const int* __restrict__ sIds,
                                           char* sX, int tid, int base) {
    float4 v[CNT];
    int doff[CNT];
    #pragma unroll
    for (int i = 0; i < CNT; ++i) {
        int c = tid + (base + i) * 256;
        bool ok = (c < NCHUNK);
        int cc = ok ? c : 0;
        int seg = cc / 25;
        int off = (cc - seg * 25) * 4;
        size_t id = (size_t)sIds[seg];
        v[i] = *(const float4*)(embf + id * DD + off);   // 16B aligned (400%16==0)
        doff[i] = ok ? gather_dst_off(cc) : -1;
    }
    #pragma unroll
    for (int i = 0; i < CNT; ++i) {
        if (doff[i] >= 0) {
            b4v pk = { (__bf16)v[i].x, (__bf16)v[i].y, (__bf16)v[i].z, (__bf16)v[i].w };
            *(b4v*)(sX + doff[i]) = pk;
        }
    }
}

template <int CNT>
__device__ __forceinline__ void gather_bf16(const __hip_bfloat16* __restrict__ embh,
                                            const int* __restrict__ sIds,
                                            char* sX, int tid, int base) {
    uint2 v[CNT];
    int doff[CNT];
    #pragma unroll
    for (int i = 0; i < CNT; ++i) {
        int c = tid + (base + i) * 256;
        bool ok = (c < NCHUNK);
        int cc = ok ? c : 0;
        int seg = cc / 25;
        int off = (cc - seg * 25) * 4;
        size_t id = (size_t)sIds[seg];
        v[i] = *(const uint2*)(embh + id * DD + off);    // 8B aligned (200%8==0)
        doff[i] = ok ? gather_dst_off(cc) : -1;
    }
    #pragma unroll
    for (int i = 0; i < CNT; ++i) {
        if (doff[i] >= 0) *(uint2*)(sX + doff[i]) = v[i];
    }
}

__global__ __launch_bounds__(256, 4) void fused_outer_encoder(
    const int* __restrict__ ids,              // int32 or int64 (flagged)
    const void* __restrict__ emb_raw,         // fp32 or bf16 (flagged), [V][DD]
    const void* __restrict__ ws,
    float* __restrict__ out)                  // [NBT][TWO_D] fp32
{
    // Only KK=50 rows staged; MFMA A-rows >= 50 are clamped to row 0 (their
    // results are discarded by the kt<KK guards), so no zero-padding rows needed.
    // sXht and sXrl live in one shared block so gather uses one int offset.
    __shared__ char sX[XHT_BYTES + XRL_BYTES];
    __shared__ int   sIds[KK * 3];
    __shared__ float sE[64];
    __shared__ float sAl[KK];
    __hip_bfloat16* sXht = (__hip_bfloat16*)sX;
    __hip_bfloat16* sXrl = (__hip_bfloat16*)(sX + XHT_BYTES);

    const int* flags = (const int*)ws;
    const __hip_bfloat16* whtp = (const __hip_bfloat16*)((const char*)ws + WS_WHT);
    const __hip_bfloat16* wrlp = (const __hip_bfloat16*)((const char*)ws + WS_WRL);
    const __hip_bfloat16* bhtp = (const __hip_bfloat16*)((const char*)ws + WS_BHT);
    const __hip_bfloat16* brlp = (const __hip_bfloat16*)((const char*)ws + WS_BRL);

    const int tid = threadIdx.x;
    const int bt  = blockIdx.x;
    const bool f32      = flags[0] != 0;
    const int idsStride = flags[1] ? 2 : 1;   // int64: read low word

    // ---- issue ids load first (latency overlaps the pad-zeroing stores) ----
    int myid = 0;
    if (tid < KK * 3) myid = ids[(bt * (KK * 3) + tid) * idsStride];

    // ---- zero ONLY the K-pad columns (they multiply zeroed W cols, but NaN
    //      garbage would poison 0*NaN). Data cols [0,200)/[0,100) get fully
    //      overwritten by the gather. ----
    for (int i = tid; i < KK * 16; i += 256) {           // ht cols [200,232): 16 uints/row
        int r = i >> 4, cw = i & 15;
        ((unsigned int*)(sXht + r * XHT_PITCH + 200))[cw] = 0u;
    }
    for (int i = tid; i < KK * 18; i += 256) {           // rl cols [100,136): 18 uints/row
        int r = i / 18, cw = i - r * 18;
        ((unsigned int*)(sXrl + r * XRL_PITCH + 100))[cw] = 0u;
    }
    if (tid < KK * 3) sIds[tid] = myid;
    __syncthreads();

    // ---- gather emb rows -> LDS bf16; 15 chunks/thread in 8+7 deep batches ----
    if (f32) {
        const float* embf = (const float*)emb_raw;
        gather_f32<8>(embf, sIds, sX, tid, 0);
        gather_f32<7>(embf, sIds, sX, tid, 8);
    } else {
        const __hip_bfloat16* embh = (const __hip_bfloat16*)emb_raw;
        gather_bf16<8>(embh, sIds, sX, tid, 0);
        gather_bf16<7>(embh, sIds, sX, tid, 8);
    }
    __syncthreads();

    const int lane = tid & 63;
    const int w    = tid >> 6;        // wave id: rows [w*16, w*16+16)
    const int n    = lane & 15;       // tile col (output feature selector)
    const int q    = lane >> 4;       // quad
    const int arow = w * 16 + n;      // A-fragment row for this lane
    const int arc  = (arow < KK) ? arow : 0;   // clamp: rows >= KK are don't-care

    // ---- head_tail GEMM: C[m][d] = sum_f X[m][f] * Wht[d][f]; K=224 (7 ksteps) ----
    f32x4 accH[7];
    #pragma unroll
    for (int t = 0; t < 7; t++) {
        #pragma unroll
        for (int j = 0; j < 4; j++) accH[t][j] = 0.f;
    }
    #pragma unroll
    for (int ks = 0; ks < 7; ks++) {
        s8v a = *(const s8v*)(sXht + arc * XHT_PITCH + ks * 32 + q * 8);
        #pragma unroll
        for (int nt = 0; nt < 7; nt++) {
            s8v b = *(const s8v*)(whtp + (nt * 16 + n) * KHT + ks * 32 + q * 8);
            accH[nt] = mfma16x16x32_bf16(a, b, accH[nt]);
        }
    }

    // bias + tanh (padded d: acc=0, bias=0 -> tanh(0)=0 -> zero contribution)
    float htv[7][4];
    #pragma unroll
    for (int nt = 0; nt < 7; nt++) {
        const float bias = bf2f(bhtp[nt * 16 + n]);
        #pragma unroll
        for (int j = 0; j < 4; j++) htv[nt][j] = tanh_fast(accH[nt][j] + bias);
    }

    // ---- relation GEMM: K=128 (4 ksteps) ----
    f32x4 accR[7];
    #pragma unroll
    for (int t = 0; t < 7; t++) {
        #pragma unroll
        for (int j = 0; j < 4; j++) accR[t][j] = 0.f;
    }
    #pragma unroll
    for (int ks = 0; ks < 4; ks++) {
        s8v a = *(const s8v*)(sXrl + arc * XRL_PITCH + ks * 32 + q * 8);
        #pragma unroll
        for (int nt = 0; nt < 7; nt++) {
            s8v b = *(const s8v*)(wrlp + (nt * 16 + n) * KRL + ks * 32 + q * 8);
            accR[nt] = mfma16x16x32_bf16(a, b, accR[nt]);
        }
    }

    // ---- e_weight: rowwise dot(rel_t, ht_t); reduce over the 16 n-lanes of each quad ----
    float dj[4];
    #pragma unroll
    for (int j = 0; j < 4; j++) dj[j] = 0.f;
    #pragma unroll
    for (int nt = 0; nt < 7; nt++) {
        const float bias = bf2f(brlp[nt * 16 + n]);
        #pragma unroll
        for (int j = 0; j < 4; j++) dj[j] += (accR[nt][j] + bias) * htv[nt][j];
    }
    #pragma unroll
    for (int mask = 1; mask < 16; mask <<= 1) {
        #pragma unroll
        for (int j = 0; j < 4; j++) dj[j] += __shfl_xor(dj[j], mask, 64);
    }
    if (n == 0) {
        #pragma unroll
        for (int j = 0; j < 4; j++) {
            const int kt = w * 16 + q * 4 + j;   // C/D row = quad*4 + reg
            if (kt < KK) sE[kt] = dj[j];
        }
    }
    __syncthreads();

    // ---- softmax over KK triples (wave 0) ----
    if (tid < 64) {
        float v = (tid < KK) ? sE[tid] : -3.0e38f;
        float mx = v;
        #pragma unroll
        for (int mask = 1; mask < 64; mask <<= 1) mx = fmaxf(mx, __shfl_xor(mx, mask, 64));
        float p = (tid < KK) ? __expf(v - mx) : 0.f;
        float s = p;
        #pragma unroll
        for (int mask = 1; mask < 64; mask <<= 1) s += __shfl_xor(s, mask, 64);
        if (tid < KK) sAl[tid] = p / s;
    }
    __syncthreads();

    // ---- output (fp32): out[bt][d] = sum_k alpha[k] * head_tail[k][d] ----
    // Re-gather from global emb in full fp32 precision (rows are L2-hot: this
    // block just staged them). d<100 -> head row, d>=100 -> tail row.
    if (tid < TWO_D) {
        const int half  = tid / DD;            // 0=head, 1=tail
        const int dmod  = tid - half * DD;
        const int whoff = half ? 2 : 0;
        float acc = 0.f;
        if (f32) {
            const float* embf = (const float*)emb_raw;
            #pragma unroll 10
            for (int k = 0; k < KK; k++) {
                size_t id = (size_t)sIds[k * 3 + whoff];
                acc += sAl[k] * embf[id * DD + dmod];
            }
        } else {
            const __hip_bfloat16* embh = (const __hip_bfloat16*)emb_raw;
            #pragma unroll 10
            for (int k = 0; k < KK; k++) {
                size_t id = (size_t)sIds[k * 3 + whoff];
                acc += sAl[k] * bf2f(embh[id * DD + dmod]);
            }
        }
        out[(size_t)bt * TWO_D + tid] = acc;
    }
}

extern "C" void kernel_launch(void* const* d_in, const int* in_sizes, int n_in,
                              void* d_out, int out_size, void* d_ws, size_t ws_size,
                              hipStream_t stream) {
    const int*  ids = (const int*)d_in[1];
    const void* emb = d_in[3];
    const void* Wht = d_in[4];
    const void* bht = d_in[5];
    const void* Wrl = d_in[6];
    const void* brl = d_in[7];
    float* out = (float*)d_out;

    const int nbt = in_sizes[1] / (KK * 3);   // B*T blocks

    hipLaunchKernelGGL(detect_dtypes, dim3(1), dim3(64), 0, stream,
                       (const unsigned int*)emb, (const unsigned int*)ids, (int*)d_ws);
    hipLaunchKernelGGL(prep_weights, dim3(64), dim3(256), 0, stream,
                       Wht, bht, Wrl, brl, d_ws);
    hipLaunchKernelGGL(fused_outer_encoder, dim3(nbt), dim3(256), 0, stream,
                       ids, emb, (const void*)d_ws, out);
}